// Round 8
// baseline (288.575 us; speedup 1.0000x reference)
//
#include <hip/hip_runtime.h>

// ---------------------------------------------------------------------------
// GIN: 3 x (bucket gather-sum + (x+agg)@W + b, relu) + MLP head, bf16 MFMA.
// r8 = r7 minus the spill: r7's depth-8 double-buffer + __launch_bounds__(256,4)
// forced scratch spills (WRITE_SIZE 2->46MB). Fix: depth-4 double buffer
// (32 VGPRs of payload) and default wave bound. Structure kept:
//  - self-edge prepended; gather = boundary-flush scan over sorted edges.
//  - per-group contiguous edge-balanced ranges; ~1KB in flight per group.
//  - 32-node tiles (1563 blocks).
// 6 dispatches: prep_all, bin_edges, sort_buckets, 2x fused_layer, l3_head.
// ---------------------------------------------------------------------------

typedef short short8 __attribute__((ext_vector_type(8)));
typedef float v4f __attribute__((ext_vector_type(4)));

#define BCAP 1024     // per-64-node-bucket capacity (edges+selves; avg 832)
#define MAXB 1024     // >= nbuckets (782)
#define SCAP 640      // per-32-node-tile staged edges (avg 416, +11 sigma)

__device__ inline unsigned short f2bf(float f) {
  union { float f; unsigned int u; } c; c.f = f;
  unsigned int u = c.u;
  return (unsigned short)((u + 0x7fffu + ((u >> 16) & 1u)) >> 16);  // RNE
}
__device__ inline float bfbits2f(unsigned int hi) {
  union { unsigned int u; float f; } c; c.u = hi; return c.f;
}
__device__ inline unsigned int pack2(float a, float b) {
  return (unsigned int)f2bf(a) | ((unsigned int)f2bf(b) << 16);
}
__device__ inline void add8(float* s, uint4 v) {
  s[0] += bfbits2f(v.x << 16); s[1] += bfbits2f(v.x & 0xffff0000u);
  s[2] += bfbits2f(v.y << 16); s[3] += bfbits2f(v.y & 0xffff0000u);
  s[4] += bfbits2f(v.z << 16); s[5] += bfbits2f(v.z & 0xffff0000u);
  s[6] += bfbits2f(v.w << 16); s[7] += bfbits2f(v.w & 0xffff0000u);
}
__device__ inline int wave_incl_scan_int(int v, int lane) {
#pragma unroll
  for (int off = 1; off < 64; off <<= 1) {
    int t = __shfl_up(v, off, 64);
    if (lane >= off) v += t;
  }
  return v;
}

// ------------------------- prep: weights + x->bf16 + zero bcnt --------------
__global__ __launch_bounds__(256) void prep_all(
    const float* __restrict__ W0, const float* __restrict__ W1, const float* __restrict__ W2,
    const float* __restrict__ Wm1, const float* __restrict__ Wm2,
    unsigned short* __restrict__ W0T, unsigned short* __restrict__ W1T,
    unsigned short* __restrict__ W2T, unsigned short* __restrict__ Wm1T,
    unsigned short* __restrict__ Wm2T,
    const float* __restrict__ x, unsigned short* __restrict__ xb, int n8,
    int* __restrict__ bcnt) {
  int i = blockIdx.x * 256 + threadIdx.x;
  if (i < MAXB) bcnt[i] = 0;
  if (i < n8) {
    const float4* p = (const float4*)x;
    float4 a = p[2 * (size_t)i], b = p[2 * (size_t)i + 1];
    uint4 o;
    o.x = pack2(a.x, a.y); o.y = pack2(a.z, a.w);
    o.z = pack2(b.x, b.y); o.w = pack2(b.z, b.w);
    ((uint4*)xb)[i] = o;
  }
  if (i < 49152) {                       // 3 x [128,128] -> [128n][128k]
    int w = i / 16384, r = i % 16384;
    int nn = r >> 7, k = r & 127;
    const float* W = (w == 0) ? W0 : (w == 1) ? W1 : W2;
    unsigned short* O = (w == 0) ? W0T : (w == 1) ? W1T : W2T;
    O[r] = f2bf(W[k * 128 + nn]);
  } else if (i < 49152 + 32768) {        // Wm1 [128,256] -> [256n][128k]
    int r = i - 49152;
    int nn = r >> 7, k = r & 127;
    Wm1T[r] = f2bf(Wm1[k * 256 + nn]);
  } else if (i < 49152 + 32768 + 4096) { // Wm2 [256,10] -> [16n][256k], pad 0
    int r = i - 49152 - 32768;
    int nn = r >> 8, k = r & 255;
    Wm2T[r] = (nn < 10) ? f2bf(Wm2[k * 10 + nn]) : (unsigned short)0;
  }
}

// ------------------------- bin edges into 64-node buckets -------------------
// entry = (src << 6) | (dst & 63); bucket = dst >> 6.
__global__ __launch_bounds__(256) void bin_edges(
    const int* __restrict__ src, const int* __restrict__ dst, int E, int per,
    int* __restrict__ bcnt, int* __restrict__ bucketA, int nbuckets) {
  __shared__ int hist[MAXB];
  __shared__ int base[MAXB];
  const int tid = threadIdx.x;
  const int e0 = blockIdx.x * per;
  const int e1 = (e0 + per < E) ? e0 + per : E;
  for (int j = tid; j < nbuckets; j += 256) hist[j] = 0;
  __syncthreads();
  for (int i = e0 + tid; i < e1; i += 256) atomicAdd(&hist[dst[i] >> 6], 1);
  __syncthreads();
  for (int j = tid; j < nbuckets; j += 256) {
    int h = hist[j];
    base[j] = h ? atomicAdd(&bcnt[j], h) : 0;
  }
  __syncthreads();
  for (int i = e0 + tid; i < e1; i += 256) {
    int d = dst[i], s = src[i];
    int b = d >> 6;
    int r = atomicAdd(&base[b], 1);
    bucketA[(size_t)b * BCAP + r] = (s << 6) | (d & 63);
  }
}

// ------------------------- per-bucket counting sort (once) ------------------
// Prepends each real node's SELF index as its first entry, then the in-edge
// srcs, all sorted by local node. boffs[b*65 + 0..64] include self slots.
__global__ __launch_bounds__(256) void sort_buckets(
    const int* __restrict__ bcnt, const int* __restrict__ bucketA,
    int* __restrict__ srcsS, int* __restrict__ boffs, int N) {
  __shared__ int rawE[BCAP];
  __shared__ int hist[64], cur[64], offs[65];
  const int tid = threadIdx.x;
  const int b = blockIdx.x;
  const int blk = b * 64;
  const int cnt = bcnt[b];
  for (int i = tid; i < cnt; i += 256) rawE[i] = bucketA[(size_t)b * BCAP + i];
  if (tid < 64) hist[tid] = (blk + tid < N) ? 1 : 0;   // self slot
  __syncthreads();
  for (int i = tid; i < cnt; i += 256) atomicAdd(&hist[rawE[i] & 63], 1);
  __syncthreads();
  if (tid < 64) {
    int v = hist[tid];
    int incl = wave_incl_scan_int(v, tid);
    int ex = incl - v;
    offs[tid] = ex;
    bool real = (blk + tid < N);
    cur[tid] = ex + (real ? 1 : 0);
    if (real) srcsS[(size_t)b * BCAP + ex] = blk + tid;  // self entry first
    if (tid == 63) offs[64] = incl;
  }
  __syncthreads();
  for (int i = tid; i < cnt; i += 256) {
    int e = rawE[i];
    int p = atomicAdd(&cur[e & 63], 1);
    srcsS[(size_t)b * BCAP + p] = e >> 6;
  }
  if (tid < 65) boffs[b * 65 + tid] = offs[tid];
}

// ------------------------- gather (shared by layer kernels) -----------------
// 16 groups x 16 lanes; group g sums rows for its contiguous edge slice
// [offsL[B[g]], offsL[B[g+1]]) with a double-buffered 4-deep load pipeline
// (2x4 uint4 = 32 VGPRs payload -> no spill), flushing bf16 rows to As at
// node boundaries (self term is edge 0).
__device__ inline void gather32(const uint4* __restrict__ base,
                                const int* __restrict__ srcS,
                                const int* __restrict__ offsL,
                                const int* __restrict__ bgrp,
                                unsigned short* __restrict__ As, int tid) {
  const int g = tid >> 4, l = tid & 15;
  int n = bgrp[g], nEnd = bgrp[g + 1];
  if (n >= nEnd) return;
  int e = offsL[n];
  const int eEnd = offsL[nEnd];
  int bound = offsL[n + 1];
  float s[8] = {0, 0, 0, 0, 0, 0, 0, 0};

  auto flush = [&](int nn) {
    uint4 o;
    o.x = pack2(s[0], s[1]); o.y = pack2(s[2], s[3]);
    o.z = pack2(s[4], s[5]); o.w = pack2(s[6], s[7]);
    *(uint4*)&As[nn * 136 + l * 8] = o;
    s[0] = s[1] = s[2] = s[3] = s[4] = s[5] = s[6] = s[7] = 0.f;
  };
  auto loadB = [&](uint4* buf, int eb) {
#pragma unroll
    for (int k2 = 0; k2 < 4; ++k2) {
      int ei = eb + k2;
      if (ei < eEnd) buf[k2] = base[(size_t)srcS[ei] * 16 + l];
    }
  };
  auto procB = [&](uint4* buf, int eb) {
#pragma unroll
    for (int k2 = 0; k2 < 4; ++k2) {
      int ei = eb + k2;
      if (ei >= eEnd) break;
      while (ei >= bound) { flush(n); ++n; bound = offsL[n + 1]; }
      add8(s, buf[k2]);
    }
  };

  uint4 b0[4], b1[4];
  loadB(b0, e);
  while (true) {
    if (e + 4 < eEnd) loadB(b1, e + 4);
    procB(b0, e); e += 4;
    if (e >= eEnd) break;
    if (e + 4 < eEnd) loadB(b0, e + 4);
    procB(b1, e); e += 4;
    if (e >= eEnd) break;
  }
  while (n < nEnd) { flush(n); ++n; }    // final node (+ rare empties)
}

// Stages offs/srcs/group-boundaries for tile (q = bucket, h = half).
__device__ inline void stage32(const int* __restrict__ srcsS,
                               const int* __restrict__ boffs,
                               int q, int h, int* offsL, int* srcS, int* bgrp,
                               int tid) {
  const int rawBase = q * 65 + h * 32;
  const int base0 = boffs[rawBase];
  if (tid < 33) offsL[tid] = boffs[rawBase + tid] - base0;
  __syncthreads();
  const int cnt = offsL[32];
  for (int i = tid; i < cnt; i += 256) srcS[i] = srcsS[(size_t)q * BCAP + base0 + i];
  if (tid < 17) {
    int target = (cnt * tid) >> 4;
    int bb = 0;
    while (bb < 32 && offsL[bb] < target) ++bb;
    bgrp[tid] = bb;
  }
  __syncthreads();
}

// ------------------------- fused layer (layers 1,2) -------------------------
// 32-node tile: gather -> As[32,136] -> C[32,128] = relu(As @ BT^T + bias).
__global__ __launch_bounds__(256) void fused_layer(
    const unsigned short* __restrict__ X, const int* __restrict__ srcsS,
    const int* __restrict__ boffs, const unsigned short* __restrict__ BT,
    const float* __restrict__ bias, unsigned short* __restrict__ C, int M) {
  __shared__ __align__(16) unsigned short As[32 * 136];
  __shared__ int srcS[SCAP];
  __shared__ int offsL[33];
  __shared__ int bgrp[17];
  const int tid = threadIdx.x;
  const int blk = blockIdx.x * 32;

  stage32(srcsS, boffs, blockIdx.x >> 1, blockIdx.x & 1, offsL, srcS, bgrp, tid);
  gather32((const uint4*)X, srcS, offsL, bgrp, As, tid);
  __syncthreads();

  // MFMA: 4 waves 2x2; wave tile 16m x 64n; K=128
  const int lane = tid & 63, w = tid >> 6;
  const int wm = w & 1, wn = w >> 1;
  const int l15 = lane & 15, quad = lane >> 4;
  const int mb = wm * 16, nb2 = wn * 64;

  const unsigned short* bp[4];
#pragma unroll
  for (int nf = 0; nf < 4; ++nf)
    bp[nf] = BT + (size_t)(nb2 + nf * 16 + l15) * 128 + quad * 8;

  v4f acc[4];
#pragma unroll
  for (int nf = 0; nf < 4; ++nf) acc[nf] = (v4f)0.f;

#pragma unroll
  for (int k0 = 0; k0 < 128; k0 += 32) {
    short8 a = *(const short8*)&As[(mb + l15) * 136 + k0 + quad * 8];
#pragma unroll
    for (int nf = 0; nf < 4; ++nf) {
      short8 bv = *(const short8*)(bp[nf] + k0);
      acc[nf] = __builtin_amdgcn_mfma_f32_16x16x32_bf16(a, bv, acc[nf], 0, 0, 0);
    }
  }

#pragma unroll
  for (int r = 0; r < 4; ++r) {
    int grow = blk + mb + quad * 4 + r;
    if (grow >= M) continue;
#pragma unroll
    for (int nf = 0; nf < 4; ++nf) {
      int gcol = nb2 + nf * 16 + l15;
      C[(size_t)grow * 128 + gcol] = f2bf(fmaxf(acc[nf][r] + bias[gcol], 0.f));
    }
  }
}

// ------------------------- fused layer 3 + MLP head -------------------------
__global__ __launch_bounds__(256) void fused_l3_head(
    const unsigned short* __restrict__ X, const int* __restrict__ srcsS,
    const int* __restrict__ boffs, const unsigned short* __restrict__ W2T,
    const float* __restrict__ b2, const unsigned short* __restrict__ Wm1T,
    const float* __restrict__ bm1, const unsigned short* __restrict__ Wm2T,
    const float* __restrict__ bm2, float* __restrict__ out, int M, int NOUT) {
  __shared__ __align__(16) unsigned short As[32 * 136];
  __shared__ __align__(16) unsigned short Hs[32 * 264];
  __shared__ int srcS[SCAP];
  __shared__ int offsL[33];
  __shared__ int bgrp[17];
  const int tid = threadIdx.x;
  const int blk = blockIdx.x * 32;

  stage32(srcsS, boffs, blockIdx.x >> 1, blockIdx.x & 1, offsL, srcS, bgrp, tid);
  gather32((const uint4*)X, srcS, offsL, bgrp, As, tid);
  __syncthreads();

  const int lane = tid & 63, w = tid >> 6;
  const int wm = w & 1, wn = w >> 1;
  const int l15 = lane & 15, quad = lane >> 4;
  const int mb = wm * 16;

  // ---- layer-3 MFMA: 32x128, K=128; wave tile 16m x 64n
  const int nb2 = wn * 64;
  v4f acc[4];
#pragma unroll
  for (int nf = 0; nf < 4; ++nf) acc[nf] = (v4f)0.f;
#pragma unroll
  for (int k0 = 0; k0 < 128; k0 += 32) {
    short8 a = *(const short8*)&As[(mb + l15) * 136 + k0 + quad * 8];
#pragma unroll
    for (int nf = 0; nf < 4; ++nf) {
      short8 bv = *(const short8*)(W2T + (size_t)(nb2 + nf * 16 + l15) * 128 + quad * 8 + k0);
      acc[nf] = __builtin_amdgcn_mfma_f32_16x16x32_bf16(a, bv, acc[nf], 0, 0, 0);
    }
  }
  __syncthreads();  // As reads done before rewrite

  // t = relu(acc + b2) -> back into As
#pragma unroll
  for (int r = 0; r < 4; ++r) {
    int row = mb + quad * 4 + r;
#pragma unroll
    for (int nf = 0; nf < 4; ++nf) {
      int col = nb2 + nf * 16 + l15;
      As[row * 136 + col] = f2bf(fmaxf(acc[nf][r] + b2[col], 0.f));
    }
  }
  __syncthreads();

  // ---- head phase A: Hs = relu(t @ Wm1 + bm1); 32x256, K=128; wave 16m x 128n
  const int nbH = wn * 128;
  v4f acc2[8];
#pragma unroll
  for (int nf = 0; nf < 8; ++nf) acc2[nf] = (v4f)0.f;
#pragma unroll
  for (int k0 = 0; k0 < 128; k0 += 32) {
    short8 a = *(const short8*)&As[(mb + l15) * 136 + k0 + quad * 8];
#pragma unroll
    for (int nf = 0; nf < 8; ++nf) {
      short8 bv = *(const short8*)(Wm1T + (size_t)(nbH + nf * 16 + l15) * 128 + quad * 8 + k0);
      acc2[nf] = __builtin_amdgcn_mfma_f32_16x16x32_bf16(a, bv, acc2[nf], 0, 0, 0);
    }
  }
#pragma unroll
  for (int r = 0; r < 4; ++r) {
    int row = mb + quad * 4 + r;
#pragma unroll
    for (int nf = 0; nf < 8; ++nf) {
      int col = nbH + nf * 16 + l15;
      Hs[row * 264 + col] = f2bf(fmaxf(acc2[nf][r] + bm1[col], 0.f));
    }
  }
  __syncthreads();

  // ---- head phase B: out = Hs @ Wm2 + bm2; 32x16, K=256; waves 0,1
  if (w < 2) {
    const int rowl = w * 16 + l15;
    const unsigned short* bp2 = Wm2T + (size_t)l15 * 256 + quad * 8;
    v4f acc3 = (v4f)0.f;
#pragma unroll
    for (int k0 = 0; k0 < 256; k0 += 32)
      acc3 = __builtin_amdgcn_mfma_f32_16x16x32_bf16(
          *(const short8*)&Hs[rowl * 264 + k0 + quad * 8],
          *(const short8*)(bp2 + k0), acc3, 0, 0, 0);
    float bb = (l15 < NOUT) ? bm2[l15] : 0.f;
#pragma unroll
    for (int r = 0; r < 4; ++r) {
      int grow = blk + w * 16 + quad * 4 + r;
      if (grow < M && l15 < NOUT) out[(size_t)grow * NOUT + l15] = acc3[r] + bb;
    }
  }
}

// ---------------------------------------------------------------------------

extern "C" void kernel_launch(void* const* d_in, const int* in_sizes, int n_in,
                              void* d_out, int out_size, void* d_ws, size_t ws_size,
                              hipStream_t stream) {
  const float* x   = (const float*)d_in[0];
  const int*   ei  = (const int*)d_in[1];
  const float* W0  = (const float*)d_in[2];
  const float* b0  = (const float*)d_in[3];
  const float* W1  = (const float*)d_in[4];
  const float* b1  = (const float*)d_in[5];
  const float* W2  = (const float*)d_in[6];
  const float* b2  = (const float*)d_in[7];
  const float* Wm1 = (const float*)d_in[8];
  const float* bm1 = (const float*)d_in[9];
  const float* Wm2 = (const float*)d_in[10];
  const float* bm2 = (const float*)d_in[11];
  float* out = (float*)d_out;

  const int D = 128;
  const int N = in_sizes[0] / D;   // 50000
  const int E = in_sizes[1] / 2;   // 600000
  const int L = in_sizes[11];      // 10
  const int nb = (N + 63) / 64;    // 782 buckets

  const int* srcv = ei;
  const int* dstv = ei + E;

  char* ws = (char*)d_ws;
  size_t off = 0;
  auto alloc = [&](size_t bytes) -> void* {
    void* p = ws + off;
    off = (off + bytes + 255) & ~(size_t)255;
    return p;
  };
  int* bcnt    = (int*)alloc((size_t)MAXB * 4);
  int* bucketA = (int*)alloc((size_t)nb * BCAP * 4);
  int* srcsS   = (int*)alloc((size_t)nb * BCAP * 4);
  int* boffs   = (int*)alloc((size_t)nb * 65 * 4);
  unsigned short* xb   = (unsigned short*)alloc((size_t)N * 128 * 2);
  unsigned short* h1   = (unsigned short*)alloc((size_t)N * 128 * 2);
  unsigned short* h2   = (unsigned short*)alloc((size_t)N * 128 * 2);
  unsigned short* W0T  = (unsigned short*)alloc(128 * 128 * 2);
  unsigned short* W1T  = (unsigned short*)alloc(128 * 128 * 2);
  unsigned short* W2T  = (unsigned short*)alloc(128 * 128 * 2);
  unsigned short* Wm1T = (unsigned short*)alloc(256 * 128 * 2);
  unsigned short* Wm2T = (unsigned short*)alloc(16 * 256 * 2);
  (void)ws_size; (void)n_in; (void)out_size;

  const int tpb = 256;
  int n8 = N * 16;
  prep_all<<<dim3((n8 + tpb - 1) / tpb), dim3(tpb), 0, stream>>>(
      W0, W1, W2, Wm1, Wm2, W0T, W1T, W2T, Wm1T, Wm2T, x, xb, n8, bcnt);

  const int nbin = 128;
  int per = (E + nbin - 1) / nbin;
  bin_edges<<<dim3(nbin), dim3(tpb), 0, stream>>>(srcv, dstv, E, per, bcnt, bucketA, nb);
  sort_buckets<<<dim3(nb), dim3(tpb), 0, stream>>>(bcnt, bucketA, srcsS, boffs, N);

  dim3 lgrid((N + 31) / 32);   // 1563 x 32-node tiles
  fused_layer<<<lgrid, dim3(tpb), 0, stream>>>(xb, srcsS, boffs, W0T, b0, h1, N);
  fused_layer<<<lgrid, dim3(tpb), 0, stream>>>(h1, srcsS, boffs, W1T, b1, h2, N);
  fused_l3_head<<<lgrid, dim3(tpb), 0, stream>>>(h2, srcsS, boffs, W2T, b2,
                                                 Wm1T, bm1, Wm2T, bm2, out, N, L);
}

// Round 9
// 247.070 us; speedup vs baseline: 1.1680x; 1.1680x over previous
//
#include <hip/hip_runtime.h>

// ---------------------------------------------------------------------------
// GIN: 3 x (bucket gather-sum + (x+agg)@W + b, relu) + MLP head, bf16 MFMA.
// r9 = r6 skeleton (64-node tiles; best measured) + branch-free uniform gather:
//  - srcsPad[node][16]: first <=16 sorted srcs, dummies -> zero row (index N).
//    Inner loop: 1 idx load + self + 16 shfl-broadcast row loads + 17 add8,
//    NO branches -> compiler issues all loads back-to-back (~4.3KB/group MLP).
//  - overflow (deg>16, ~10% nodes) via short trailing loop over sorted list.
//  - xb/h1/h2 have N+1 rows; row N zeroed every call in prep_all.
// 6 dispatches: prep_all, bin_edges, sort_buckets, 2x fused_layer, l3_head.
// ---------------------------------------------------------------------------

typedef short short8 __attribute__((ext_vector_type(8)));
typedef float v4f __attribute__((ext_vector_type(4)));

#define BCAP 1024   // per-64-node-bucket edge capacity (avg 768, +9 sigma)
#define MAXB 1024   // >= nbuckets (782)

__device__ inline unsigned short f2bf(float f) {
  union { float f; unsigned int u; } c; c.f = f;
  unsigned int u = c.u;
  return (unsigned short)((u + 0x7fffu + ((u >> 16) & 1u)) >> 16);  // RNE
}
__device__ inline float bfbits2f(unsigned int hi) {
  union { unsigned int u; float f; } c; c.u = hi; return c.f;
}
__device__ inline unsigned int pack2(float a, float b) {
  return (unsigned int)f2bf(a) | ((unsigned int)f2bf(b) << 16);
}
__device__ inline void add8(float* s, uint4 v) {
  s[0] += bfbits2f(v.x << 16); s[1] += bfbits2f(v.x & 0xffff0000u);
  s[2] += bfbits2f(v.y << 16); s[3] += bfbits2f(v.y & 0xffff0000u);
  s[4] += bfbits2f(v.z << 16); s[5] += bfbits2f(v.z & 0xffff0000u);
  s[6] += bfbits2f(v.w << 16); s[7] += bfbits2f(v.w & 0xffff0000u);
}
__device__ inline int wave_incl_scan_int(int v, int lane) {
#pragma unroll
  for (int off = 1; off < 64; off <<= 1) {
    int t = __shfl_up(v, off, 64);
    if (lane >= off) v += t;
  }
  return v;
}

// ------------------------- prep: weights + x->bf16 + zero rows/bcnt ---------
__global__ __launch_bounds__(256) void prep_all(
    const float* __restrict__ W0, const float* __restrict__ W1, const float* __restrict__ W2,
    const float* __restrict__ Wm1, const float* __restrict__ Wm2,
    unsigned short* __restrict__ W0T, unsigned short* __restrict__ W1T,
    unsigned short* __restrict__ W2T, unsigned short* __restrict__ Wm1T,
    unsigned short* __restrict__ Wm2T,
    const float* __restrict__ x, unsigned short* __restrict__ xb, int n8,
    int* __restrict__ bcnt, unsigned short* __restrict__ h1,
    unsigned short* __restrict__ h2, int N) {
  int i = blockIdx.x * 256 + threadIdx.x;
  if (i < MAXB) bcnt[i] = 0;
  if (blockIdx.x == 0) {  // zero row N of xb/h1/h2 (the dummy-slot target)
    int t = threadIdx.x;
    uint4 z = make_uint4(0, 0, 0, 0);
    if (t < 16)            ((uint4*)xb)[(size_t)N * 16 + t] = z;
    else if (t < 32)       ((uint4*)h1)[(size_t)N * 16 + (t - 16)] = z;
    else if (t < 48)       ((uint4*)h2)[(size_t)N * 16 + (t - 32)] = z;
  }
  if (i < n8) {
    const float4* p = (const float4*)x;
    float4 a = p[2 * (size_t)i], b = p[2 * (size_t)i + 1];
    uint4 o;
    o.x = pack2(a.x, a.y); o.y = pack2(a.z, a.w);
    o.z = pack2(b.x, b.y); o.w = pack2(b.z, b.w);
    ((uint4*)xb)[i] = o;
  }
  if (i < 49152) {                       // 3 x [128,128] -> [128n][128k]
    int w = i / 16384, r = i % 16384;
    int nn = r >> 7, k = r & 127;
    const float* W = (w == 0) ? W0 : (w == 1) ? W1 : W2;
    unsigned short* O = (w == 0) ? W0T : (w == 1) ? W1T : W2T;
    O[r] = f2bf(W[k * 128 + nn]);
  } else if (i < 49152 + 32768) {        // Wm1 [128,256] -> [256n][128k]
    int r = i - 49152;
    int nn = r >> 7, k = r & 127;
    Wm1T[r] = f2bf(Wm1[k * 256 + nn]);
  } else if (i < 49152 + 32768 + 4096) { // Wm2 [256,10] -> [16n][256k], pad 0
    int r = i - 49152 - 32768;
    int nn = r >> 8, k = r & 255;
    Wm2T[r] = (nn < 10) ? f2bf(Wm2[k * 10 + nn]) : (unsigned short)0;
  }
}

// ------------------------- bin edges into 64-node buckets -------------------
// entry = (src << 6) | (dst & 63); bucket = dst >> 6.
__global__ __launch_bounds__(256) void bin_edges(
    const int* __restrict__ src, const int* __restrict__ dst, int E, int per,
    int* __restrict__ bcnt, int* __restrict__ bucketA, int nbuckets) {
  __shared__ int hist[MAXB];
  __shared__ int base[MAXB];
  const int tid = threadIdx.x;
  const int e0 = blockIdx.x * per;
  const int e1 = (e0 + per < E) ? e0 + per : E;
  for (int j = tid; j < nbuckets; j += 256) hist[j] = 0;
  __syncthreads();
  for (int i = e0 + tid; i < e1; i += 256) atomicAdd(&hist[dst[i] >> 6], 1);
  __syncthreads();
  for (int j = tid; j < nbuckets; j += 256) {
    int h = hist[j];
    base[j] = h ? atomicAdd(&bcnt[j], h) : 0;
  }
  __syncthreads();
  for (int i = e0 + tid; i < e1; i += 256) {
    int d = dst[i], s = src[i];
    int b = d >> 6;
    int r = atomicAdd(&base[b], 1);
    bucketA[(size_t)b * BCAP + r] = (s << 6) | (d & 63);
  }
}

// ------------------------- per-bucket sort + padded slot table --------------
// sortedS (LDS) -> srcsS contiguous + srcsPad[node][16] (dummy = N -> zero row)
// + boffs[b*65+0..64].
__global__ __launch_bounds__(256) void sort_buckets(
    const int* __restrict__ bcnt, const int* __restrict__ bucketA,
    int* __restrict__ srcsS, int* __restrict__ srcsPad,
    int* __restrict__ boffs, int N) {
  __shared__ int rawE[BCAP], sortedS[BCAP];
  __shared__ int hist[64], cur[64], offs[65];
  const int tid = threadIdx.x;
  const int b = blockIdx.x;
  const int blk = b * 64;
  const int cnt = bcnt[b];
  for (int i = tid; i < cnt; i += 256) rawE[i] = bucketA[(size_t)b * BCAP + i];
  if (tid < 64) hist[tid] = 0;
  __syncthreads();
  for (int i = tid; i < cnt; i += 256) atomicAdd(&hist[rawE[i] & 63], 1);
  __syncthreads();
  if (tid < 64) {
    int v = hist[tid];
    int incl = wave_incl_scan_int(v, tid);
    offs[tid] = incl - v;
    cur[tid] = incl - v;
    if (tid == 63) offs[64] = incl;
  }
  __syncthreads();
  for (int i = tid; i < cnt; i += 256) {
    int e = rawE[i];
    int p = atomicAdd(&cur[e & 63], 1);
    sortedS[p] = e >> 6;
  }
  __syncthreads();
  for (int i = tid; i < cnt; i += 256) srcsS[(size_t)b * BCAP + i] = sortedS[i];
  for (int idx = tid; idx < 1024; idx += 256) {
    int nl = idx >> 4, j = idx & 15;
    int beg = offs[nl], c = offs[nl + 1] - beg;
    srcsPad[((size_t)(blk + nl)) * 16 + j] = (j < c) ? sortedS[beg + j] : N;
  }
  if (tid < 65) boffs[b * 65 + tid] = offs[tid];
}

// ------------------------- uniform gather (shared) --------------------------
// 16 groups x 16 lanes; 4 sweeps; per node: idx load + self + 16 broadcast
// row loads + 17 add8, branch-free; overflow tail (deg>16) from srcsS.
__device__ inline void gather64(const uint4* __restrict__ base,
                                const int* __restrict__ srcsPad,
                                const int* __restrict__ srcsS, size_t bucketBase,
                                const int* __restrict__ offs,
                                unsigned short* __restrict__ As,
                                int blk, int M, int tid) {
  const int l = tid & 15, g = tid >> 4;
  const int gb = (tid & 63) & 48;
#pragma unroll 1
  for (int s2 = 0; s2 < 4; ++s2) {
    const int nl = s2 * 16 + g;
    const int node = blk + nl;
    const int nrow = (node < M) ? node : M;      // row M is all-zero
    const int beg = offs[nl];
    const int c = offs[nl + 1] - beg;
    const int myidx = srcsPad[(size_t)node * 16 + l];  // coalesced 64B/group
    uint4 self = base[(size_t)nrow * 16 + l];
    uint4 r[16];
#pragma unroll
    for (int j = 0; j < 16; ++j) {
      int ij = __shfl(myidx, gb + j, 64);
      r[j] = base[(size_t)ij * 16 + l];
    }
    float s[8] = {0, 0, 0, 0, 0, 0, 0, 0};
    add8(s, self);
#pragma unroll
    for (int j = 0; j < 16; ++j) add8(s, r[j]);
    for (int j = 16; j < c; ++j)                 // rare overflow tail
      add8(s, base[(size_t)srcsS[bucketBase + beg + j] * 16 + l]);
    uint4 o;
    o.x = pack2(s[0], s[1]); o.y = pack2(s[2], s[3]);
    o.z = pack2(s[4], s[5]); o.w = pack2(s[6], s[7]);
    *(uint4*)&As[nl * 136 + l * 8] = o;
  }
}

// ------------------------- fused layer (layers 1,2) -------------------------
// 64-node tile: gather -> As[64,136] -> C = relu(As @ BT^T + bias).
__global__ __launch_bounds__(256) void fused_layer(
    const unsigned short* __restrict__ X, const int* __restrict__ srcsPad,
    const int* __restrict__ srcsS, const int* __restrict__ boffs,
    const unsigned short* __restrict__ BT, const float* __restrict__ bias,
    unsigned short* __restrict__ C, int M) {
  __shared__ __align__(16) unsigned short As[64 * 136];
  __shared__ int offs[65];
  const int tid = threadIdx.x;
  const int b = blockIdx.x;
  const int blk = b * 64;
  if (tid < 65) offs[tid] = boffs[b * 65 + tid];
  __syncthreads();

  gather64((const uint4*)X, srcsPad, srcsS, (size_t)b * BCAP, offs, As, blk, M, tid);
  __syncthreads();

  // MFMA: 4 waves 2x2; wave tile 32m x 64n; K=128
  const int lane = tid & 63, w = tid >> 6;
  const int wm = w & 1, wn = w >> 1;
  const int l15 = lane & 15, quad = lane >> 4;
  const int mb = wm * 32, nb2 = wn * 64;

  const unsigned short* bp[4];
#pragma unroll
  for (int nf = 0; nf < 4; ++nf)
    bp[nf] = BT + (size_t)(nb2 + nf * 16 + l15) * 128 + quad * 8;

  v4f acc[2][4];
#pragma unroll
  for (int mf = 0; mf < 2; ++mf)
#pragma unroll
    for (int nf = 0; nf < 4; ++nf) acc[mf][nf] = (v4f)0.f;

#pragma unroll
  for (int k0 = 0; k0 < 128; k0 += 32) {
    short8 a[2], bv[4];
#pragma unroll
    for (int mf = 0; mf < 2; ++mf)
      a[mf] = *(const short8*)&As[(mb + mf * 16 + l15) * 136 + k0 + quad * 8];
#pragma unroll
    for (int nf = 0; nf < 4; ++nf) bv[nf] = *(const short8*)(bp[nf] + k0);
#pragma unroll
    for (int mf = 0; mf < 2; ++mf)
#pragma unroll
      for (int nf = 0; nf < 4; ++nf)
        acc[mf][nf] = __builtin_amdgcn_mfma_f32_16x16x32_bf16(a[mf], bv[nf], acc[mf][nf], 0, 0, 0);
  }

#pragma unroll
  for (int mf = 0; mf < 2; ++mf) {
#pragma unroll
    for (int r = 0; r < 4; ++r) {
      int grow = blk + mb + mf * 16 + quad * 4 + r;
      if (grow >= M) continue;
#pragma unroll
      for (int nf = 0; nf < 4; ++nf) {
        int gcol = nb2 + nf * 16 + l15;
        float v = acc[mf][nf][r] + bias[gcol];
        C[(size_t)grow * 128 + gcol] = f2bf(fmaxf(v, 0.f));
      }
    }
  }
}

// ------------------------- fused layer 3 + MLP head -------------------------
__global__ __launch_bounds__(256) void fused_l3_head(
    const unsigned short* __restrict__ X, const int* __restrict__ srcsPad,
    const int* __restrict__ srcsS, const int* __restrict__ boffs,
    const unsigned short* __restrict__ W2T, const float* __restrict__ b2,
    const unsigned short* __restrict__ Wm1T, const float* __restrict__ bm1,
    const unsigned short* __restrict__ Wm2T, const float* __restrict__ bm2,
    float* __restrict__ out, int M, int NOUT) {
  __shared__ __align__(16) unsigned char lds[64 * 264 * 2];  // 33.8KB union
  unsigned short* As = (unsigned short*)lds;                 // 17.4KB
  unsigned short* Hs = (unsigned short*)lds;                 // aliases As
  __shared__ int offs[65];
  const int tid = threadIdx.x;
  const int b = blockIdx.x;
  const int blk = b * 64;
  if (tid < 65) offs[tid] = boffs[b * 65 + tid];
  __syncthreads();

  gather64((const uint4*)X, srcsPad, srcsS, (size_t)b * BCAP, offs, As, blk, M, tid);
  __syncthreads();

  const int lane = tid & 63, w = tid >> 6;
  const int wm = w & 1, wn = w >> 1;
  const int l15 = lane & 15, quad = lane >> 4;
  const int mb = wm * 32;

  // ---- layer-3 MFMA: 64x128, K=128; wave tile 32m x 64n
  const int nb2 = wn * 64;
  v4f acc[2][4];
#pragma unroll
  for (int mf = 0; mf < 2; ++mf)
#pragma unroll
    for (int nf = 0; nf < 4; ++nf) acc[mf][nf] = (v4f)0.f;
#pragma unroll
  for (int k0 = 0; k0 < 128; k0 += 32) {
    short8 a[2], bv[4];
#pragma unroll
    for (int mf = 0; mf < 2; ++mf)
      a[mf] = *(const short8*)&As[(mb + mf * 16 + l15) * 136 + k0 + quad * 8];
#pragma unroll
    for (int nf = 0; nf < 4; ++nf)
      bv[nf] = *(const short8*)(W2T + (size_t)(nb2 + nf * 16 + l15) * 128 + quad * 8 + k0);
#pragma unroll
    for (int mf = 0; mf < 2; ++mf)
#pragma unroll
      for (int nf = 0; nf < 4; ++nf)
        acc[mf][nf] = __builtin_amdgcn_mfma_f32_16x16x32_bf16(a[mf], bv[nf], acc[mf][nf], 0, 0, 0);
  }
  __syncthreads();  // all As reads done before rewrite

  // t = relu(acc + b2) -> back into As
#pragma unroll
  for (int mf = 0; mf < 2; ++mf)
#pragma unroll
    for (int r = 0; r < 4; ++r) {
      int row = mb + mf * 16 + quad * 4 + r;
#pragma unroll
      for (int nf = 0; nf < 4; ++nf) {
        int col = nb2 + nf * 16 + l15;
        As[row * 136 + col] = f2bf(fmaxf(acc[mf][nf][r] + b2[col], 0.f));
      }
    }
  __syncthreads();

  // ---- head phase A: acc2 = t @ Wm1 (+bm1, relu later); 64x256, K=128
  const int nbH = wn * 128;
  v4f acc2[2][8];
#pragma unroll
  for (int mf = 0; mf < 2; ++mf)
#pragma unroll
    for (int nf = 0; nf < 8; ++nf) acc2[mf][nf] = (v4f)0.f;
#pragma unroll
  for (int k0 = 0; k0 < 128; k0 += 32) {
    short8 a[2];
#pragma unroll
    for (int mf = 0; mf < 2; ++mf)
      a[mf] = *(const short8*)&As[(mb + mf * 16 + l15) * 136 + k0 + quad * 8];
#pragma unroll
    for (int nf = 0; nf < 8; ++nf) {
      short8 bv = *(const short8*)(Wm1T + (size_t)(nbH + nf * 16 + l15) * 128 + quad * 8 + k0);
#pragma unroll
      for (int mf = 0; mf < 2; ++mf)
        acc2[mf][nf] = __builtin_amdgcn_mfma_f32_16x16x32_bf16(a[mf], bv, acc2[mf][nf], 0, 0, 0);
    }
  }
  __syncthreads();  // As reads done; Hs overwrites the union

#pragma unroll
  for (int mf = 0; mf < 2; ++mf)
#pragma unroll
    for (int r = 0; r < 4; ++r) {
      int row = mb + mf * 16 + quad * 4 + r;
#pragma unroll
      for (int nf = 0; nf < 8; ++nf) {
        int col = nbH + nf * 16 + l15;
        Hs[row * 264 + col] = f2bf(fmaxf(acc2[mf][nf][r] + bm1[col], 0.f));
      }
    }
  __syncthreads();

  // ---- head phase B: out = Hs @ Wm2 + bm2; 64x16, K=256; wave = 16 rows
  const int rowl = w * 16 + l15;
  const unsigned short* bp2 = Wm2T + (size_t)l15 * 256 + quad * 8;
  v4f acc3 = (v4f)0.f;
#pragma unroll
  for (int k0 = 0; k0 < 256; k0 += 32)
    acc3 = __builtin_amdgcn_mfma_f32_16x16x32_bf16(
        *(const short8*)&Hs[rowl * 264 + k0 + quad * 8],
        *(const short8*)(bp2 + k0), acc3, 0, 0, 0);
  float bb = (l15 < NOUT) ? bm2[l15] : 0.f;
#pragma unroll
  for (int r = 0; r < 4; ++r) {
    int grow = blk + w * 16 + quad * 4 + r;
    if (grow < M && l15 < NOUT) out[(size_t)grow * NOUT + l15] = acc3[r] + bb;
  }
}

// ---------------------------------------------------------------------------

extern "C" void kernel_launch(void* const* d_in, const int* in_sizes, int n_in,
                              void* d_out, int out_size, void* d_ws, size_t ws_size,
                              hipStream_t stream) {
  const float* x   = (const float*)d_in[0];
  const int*   ei  = (const int*)d_in[1];
  const float* W0  = (const float*)d_in[2];
  const float* b0  = (const float*)d_in[3];
  const float* W1  = (const float*)d_in[4];
  const float* b1  = (const float*)d_in[5];
  const float* W2  = (const float*)d_in[6];
  const float* b2  = (const float*)d_in[7];
  const float* Wm1 = (const float*)d_in[8];
  const float* bm1 = (const float*)d_in[9];
  const float* Wm2 = (const float*)d_in[10];
  const float* bm2 = (const float*)d_in[11];
  float* out = (float*)d_out;

  const int D = 128;
  const int N = in_sizes[0] / D;   // 50000
  const int E = in_sizes[1] / 2;   // 600000
  const int L = in_sizes[11];      // 10
  const int nb = (N + 63) / 64;    // 782 buckets == layer tiles

  const int* srcv = ei;
  const int* dstv = ei + E;

  char* ws = (char*)d_ws;
  size_t off = 0;
  auto alloc = [&](size_t bytes) -> void* {
    void* p = ws + off;
    off = (off + bytes + 255) & ~(size_t)255;
    return p;
  };
  int* bcnt    = (int*)alloc((size_t)MAXB * 4);
  int* bucketA = (int*)alloc((size_t)nb * BCAP * 4);
  int* srcsS   = (int*)alloc((size_t)nb * BCAP * 4);
  int* srcsPad = (int*)alloc((size_t)nb * 64 * 16 * 4);
  int* boffs   = (int*)alloc((size_t)nb * 65 * 4);
  unsigned short* xb   = (unsigned short*)alloc((size_t)(N + 1) * 128 * 2);
  unsigned short* h1   = (unsigned short*)alloc((size_t)(N + 1) * 128 * 2);
  unsigned short* h2   = (unsigned short*)alloc((size_t)(N + 1) * 128 * 2);
  unsigned short* W0T  = (unsigned short*)alloc(128 * 128 * 2);
  unsigned short* W1T  = (unsigned short*)alloc(128 * 128 * 2);
  unsigned short* W2T  = (unsigned short*)alloc(128 * 128 * 2);
  unsigned short* Wm1T = (unsigned short*)alloc(256 * 128 * 2);
  unsigned short* Wm2T = (unsigned short*)alloc(16 * 256 * 2);
  (void)ws_size; (void)n_in; (void)out_size;

  const int tpb = 256;
  int n8 = N * 16;
  prep_all<<<dim3((n8 + tpb - 1) / tpb), dim3(tpb), 0, stream>>>(
      W0, W1, W2, Wm1, Wm2, W0T, W1T, W2T, Wm1T, Wm2T, x, xb, n8, bcnt, h1, h2, N);

  const int nbin = 128;
  int per = (E + nbin - 1) / nbin;
  bin_edges<<<dim3(nbin), dim3(tpb), 0, stream>>>(srcv, dstv, E, per, bcnt, bucketA, nb);
  sort_buckets<<<dim3(nb), dim3(tpb), 0, stream>>>(bcnt, bucketA, srcsS, srcsPad, boffs, N);

  dim3 lgrid(nb);
  fused_layer<<<lgrid, dim3(tpb), 0, stream>>>(xb, srcsPad, srcsS, boffs, W0T, b0, h1, N);
  fused_layer<<<lgrid, dim3(tpb), 0, stream>>>(h1, srcsPad, srcsS, boffs, W1T, b1, h2, N);
  fused_l3_head<<<lgrid, dim3(tpb), 0, stream>>>(h2, srcsPad, srcsS, boffs, W2T, b2,
                                                 Wm1T, bm1, Wm2T, bm2, out, N, L);
}